// Round 2
// 317.552 us; speedup vs baseline: 1.1043x; 1.1043x over previous
//
#include <hip/hip_runtime.h>
#include <hip/hip_bf16.h>

typedef __bf16 bf16_t;
typedef __bf16 bf16x4 __attribute__((ext_vector_type(4)));
typedef __bf16 bf16x8 __attribute__((ext_vector_type(8)));
typedef float f32x4 __attribute__((ext_vector_type(4)));

#define B_    2
#define T_    2048
#define DIM_  2048
#define H_    16
#define HKV_  4
#define D_    128
#define KVDIM_ 512

// ---- helpers --------------------------------------------------------------
__device__ __forceinline__ bf16x8 cvt8(f32x4 a, f32x4 b) {
  bf16x8 r;
  r[0] = (bf16_t)a[0]; r[1] = (bf16_t)a[1]; r[2] = (bf16_t)a[2]; r[3] = (bf16_t)a[3];
  r[4] = (bf16_t)b[0]; r[5] = (bf16_t)b[1]; r[6] = (bf16_t)b[2]; r[7] = (bf16_t)b[3];
  return r;
}
__device__ __forceinline__ bf16x4 cvt4(f32x4 a) {
  bf16x4 r;
  r[0] = (bf16_t)a[0]; r[1] = (bf16_t)a[1]; r[2] = (bf16_t)a[2]; r[3] = (bf16_t)a[3];
  return r;
}
// async global->LDS, 16B per lane; LDS dest = wave-uniform base + lane*16
__device__ __forceinline__ void g2l16(const void* g, void* l) {
  __builtin_amdgcn_global_load_lds(
      (const __attribute__((address_space(1))) unsigned int*)g,
      (__attribute__((address_space(3))) unsigned int*)l, 16, 0, 0);
}

// ---------------------------------------------------------------------------
// Fused fp32 -> bf16 convert (one launch).  2048-elem blocks.
// x:4096 | Wq:2048 | Wk:512 | Wv:512 | Wp:2048  (Wq/Wk/Wv -> contiguous Wqkvb)
// ---------------------------------------------------------------------------
__global__ __launch_bounds__(256)
void cvt_all(const float* __restrict__ x,  const float* __restrict__ wq,
             const float* __restrict__ wk, const float* __restrict__ wv,
             const float* __restrict__ wp, bf16_t* __restrict__ xb,
             bf16_t* __restrict__ wqkvb, bf16_t* __restrict__ wpb) {
  int blk = blockIdx.x;
  const float* s; bf16_t* d; int lb;
  if (blk < 4096)      { s = x;  d = xb;                              lb = blk; }
  else if (blk < 6144) { s = wq; d = wqkvb;                           lb = blk - 4096; }
  else if (blk < 6656) { s = wk; d = wqkvb + (size_t)2048 * DIM_;     lb = blk - 6144; }
  else if (blk < 7168) { s = wv; d = wqkvb + (size_t)2560 * DIM_;     lb = blk - 6656; }
  else                 { s = wp; d = wpb;                             lb = blk - 7168; }
  size_t i = (size_t)lb * 2048 + (size_t)threadIdx.x * 8;
  f32x4 a = *(const f32x4*)(s + i);
  f32x4 b = *(const f32x4*)(s + i + 4);
  *(bf16x8*)(d + i) = cvt8(a, b);
}

// ---------------------------------------------------------------------------
// Legacy 128x128 GEMM (kept for the fallback path).
// ---------------------------------------------------------------------------
template <int MODE, bool AASYNC, bool WASYNC>
__global__ __launch_bounds__(256)
void gemm128(const void* __restrict__ Ag, const void* __restrict__ Wg,
             const void* __restrict__ Wg2, void* __restrict__ Cb,
             bf16_t* __restrict__ Kb, bf16_t* __restrict__ Vb,
             float* __restrict__ Vf, int M, int N, int K) {
  constexpr int LDA = AASYNC ? 32 : 40;
  constexpr int LDW = WASYNC ? 32 : 40;
  __shared__ bf16_t As[128 * LDA];
  __shared__ bf16_t Ws[128 * LDW];
  const int tid  = threadIdx.x;
  const int wave = tid >> 6, lane = tid & 63;
  const int l16  = lane & 15, lg = lane >> 4;
  const int m0 = blockIdx.y * 128, n0 = blockIdx.x * 128;
  const int wm = (wave & 1) * 64, wn = (wave >> 1) * 64;
  f32x4 acc[4][4] = {};

  for (int k0 = 0; k0 < K; k0 += 32) {
    __syncthreads();
    if constexpr (AASYNC) {
      const bf16_t* A = (const bf16_t*)Ag;
      const int r = lane >> 2, c8 = (lane & 3) * 8;
      g2l16(&A[(size_t)(m0 + wave * 32 + r) * K + k0 + c8],      &As[(wave * 32) * LDA]);
      g2l16(&A[(size_t)(m0 + wave * 32 + 16 + r) * K + k0 + c8], &As[(wave * 32 + 16) * LDA]);
    } else {
      const float* A = (const float*)Ag;
#pragma unroll
      for (int j = 0; j < 4; j++) {
        int row = wave * 32 + j * 8 + (lane >> 3);
        int cf  = (lane & 7) * 4;
        f32x4 v = *(const f32x4*)&A[(size_t)(m0 + row) * K + k0 + cf];
        *(bf16x4*)&As[row * LDA + cf] = cvt4(v);
      }
    }
    if constexpr (WASYNC) {
      const bf16_t* W = (const bf16_t*)Wg;
      const int r = lane >> 2, c8 = (lane & 3) * 8;
      g2l16(&W[(size_t)(n0 + wave * 32 + r) * K + k0 + c8],      &Ws[(wave * 32) * LDW]);
      g2l16(&W[(size_t)(n0 + wave * 32 + 16 + r) * K + k0 + c8], &Ws[(wave * 32 + 16) * LDW]);
    } else {
      const float* W;
      int nb;
      if constexpr (MODE == 3) {
        if (n0 < 512) { W = (const float*)Wg;  nb = n0; }
        else          { W = (const float*)Wg2; nb = n0 - 512; }
      } else { W = (const float*)Wg; nb = n0; }
#pragma unroll
      for (int j = 0; j < 4; j++) {
        int row = wave * 32 + j * 8 + (lane >> 3);
        int cf  = (lane & 7) * 4;
        f32x4 v = *(const f32x4*)&W[(size_t)(nb + row) * K + k0 + cf];
        *(bf16x4*)&Ws[row * LDW + cf] = cvt4(v);
      }
    }
    __syncthreads();
    bf16x8 af[4], bfr[4];
#pragma unroll
    for (int i = 0; i < 4; i++)
      af[i] = *(const bf16x8*)&As[(wm + i * 16 + l16) * LDA + lg * 8];
#pragma unroll
    for (int j = 0; j < 4; j++)
      bfr[j] = *(const bf16x8*)&Ws[(wn + j * 16 + l16) * LDW + lg * 8];
#pragma unroll
    for (int i = 0; i < 4; i++)
#pragma unroll
      for (int j = 0; j < 4; j++)
        acc[i][j] = __builtin_amdgcn_mfma_f32_16x16x32_bf16(af[i], bfr[j], acc[i][j], 0, 0, 0);
  }
#pragma unroll
  for (int i = 0; i < 4; i++)
#pragma unroll
    for (int j = 0; j < 4; j++) {
      int row = m0 + wm + i * 16 + lg * 4;
      int col = n0 + wn + j * 16 + l16;
#pragma unroll
      for (int r = 0; r < 4; r++) {
        float v = acc[i][j][r];
        if constexpr (MODE == 0) {
          ((bf16_t*)Cb)[(size_t)(row + r) * N + col] = (bf16_t)v;
        } else if constexpr (MODE == 2) {
          ((float*)Cb)[(size_t)(row + r) * N + col] = v;
        } else if constexpr (MODE == 1) {
          if (col < 2048)      ((bf16_t*)Cb)[(size_t)(row + r) * 2048 + col] = (bf16_t)v;
          else if (col < 2560) Kb[(size_t)(row + r) * 512 + (col - 2048)] = (bf16_t)v;
          else {
            int c = col - 2560;
            Vb[(size_t)(row + r) * 512 + c] = (bf16_t)v;
            Vf[(size_t)(row + r) * 512 + c] = v;
          }
        } else {  // MODE 3
          if (col < 512) ((bf16_t*)Cb)[(size_t)(row + r) * 512 + col] = (bf16_t)v;
          else {
            int c = col - 512;
            Vb[(size_t)(row + r) * 512 + c] = (bf16_t)v;
            Vf[(size_t)(row + r) * 512 + c] = v;
          }
        }
      }
    }
}

// ---------------------------------------------------------------------------
// 256x256 8-phase GEMM (T2 swizzle + T3/T4 counted vmcnt + T5 setprio).
// C[M,N] = A[M,K] @ W[N,K]^T, bf16 in, 8 waves (2Mx4N), BK=64, 128 KiB LDS
// double-buffered by K-tile parity (buf = kt&1).
// LDS map (bytes): buf*65536 + {A:0, W:32768} + row*128 + (colb ^ ((row&7)<<4))
// Staged via linear global_load_lds with the inverse-swizzled global source.
// vmcnt ledger (2 loads per stage_half):
//   ph4 wait(4): {prev ph7,ph8, ph1..ph4}=12 -> ph1/ph2 (A buf1) landed
//   ph8 wait(4): ph3..ph6 landed before next-iter ph1 reads buf0
//   last iter: wait(0) at ph4, no stages after.
// ---------------------------------------------------------------------------
#define SB() __builtin_amdgcn_sched_barrier(0)
#define BARRIER() __builtin_amdgcn_s_barrier()
#define LGKM0() do { asm volatile("s_waitcnt lgkmcnt(0)" ::: "memory"); SB(); } while (0)
#define VMW(N) do { asm volatile("s_waitcnt vmcnt(" #N ")" ::: "memory"); SB(); } while (0)

#define RD_A(BUF, QM) do { \
  _Pragma("unroll") for (int f_ = 0; f_ < 4; f_++) { \
    const int r_ = wm * 128 + (QM) * 64 + f_ * 16 + l16; \
    _Pragma("unroll") for (int ks_ = 0; ks_ < 2; ks_++) \
      a[f_][ks_] = *(const bf16x8*)(lds + (BUF) * 65536 + r_ * 128 + ((ks_ * 64 + lg * 16) ^ swz)); \
  } } while (0)

#define RD_B(BUF, QN, BB) do { \
  _Pragma("unroll") for (int n_ = 0; n_ < 2; n_++) { \
    const int r_ = wn * 64 + (QN) * 32 + n_ * 16 + l16; \
    _Pragma("unroll") for (int ks_ = 0; ks_ < 2; ks_++) \
      BB[n_][ks_] = *(const bf16x8*)(lds + (BUF) * 65536 + 32768 + r_ * 128 + ((ks_ * 64 + lg * 16) ^ swz)); \
  } } while (0)

#define MM(QM, QN, BB) do { \
  __builtin_amdgcn_s_setprio(1); \
  _Pragma("unroll") for (int f_ = 0; f_ < 4; f_++) \
    _Pragma("unroll") for (int n_ = 0; n_ < 2; n_++) \
      _Pragma("unroll") for (int ks_ = 0; ks_ < 2; ks_++) \
        acc[(QM) * 4 + f_][(QN) * 2 + n_] = __builtin_amdgcn_mfma_f32_16x16x32_bf16( \
            a[f_][ks_], BB[n_][ks_], acc[(QM) * 4 + f_][(QN) * 2 + n_], 0, 0, 0); \
  __builtin_amdgcn_s_setprio(0); \
  } while (0)

#define K_ITER(KT0, LAST) do { \
  const int kA1_ = ((KT0) + 1) * 64; \
  const int kN2_ = ((KT0) + 2) * 64; \
  const int kN3_ = ((KT0) + 3) * 64; \
  /* ph1 */ \
  RD_A(0, 0); RD_B(0, 0, b0); \
  stage_half(Ag, m0, kA1_, 65536); \
  asm volatile("s_waitcnt lgkmcnt(8)" ::: "memory"); \
  SB(); BARRIER(); LGKM0(); \
  MM(0, 0, b0); \
  SB(); BARRIER(); \
  /* ph2 */ \
  RD_B(0, 1, b1); \
  stage_half(Ag, m0 + 128, kA1_, 65536 + 16384); \
  SB(); BARRIER(); LGKM0(); \
  MM(0, 1, b1); \
  SB(); BARRIER(); \
  /* ph3 */ \
  RD_A(0, 1); \
  if (!(LAST)) stage_half(Wg, n0, kN2_, 32768); \
  SB(); BARRIER(); LGKM0(); \
  MM(1, 0, b0); \
  SB(); BARRIER(); \
  /* ph4 */ \
  if (!(LAST)) { stage_half(Wg, n0 + 128, kN2_, 32768 + 16384); VMW(4); } \
  else { VMW(0); } \
  SB(); BARRIER(); \
  MM(1, 1, b1); \
  SB(); BARRIER(); \
  /* ph5 */ \
  RD_A(1, 0); RD_B(1, 0, b0); \
  if (!(LAST)) stage_half(Ag, m0, kN2_, 0); \
  asm volatile("s_waitcnt lgkmcnt(8)" ::: "memory"); \
  SB(); BARRIER(); LGKM0(); \
  MM(0, 0, b0); \
  SB(); BARRIER(); \
  /* ph6 */ \
  RD_B(1, 1, b1); \
  if (!(LAST)) stage_half(Ag, m0 + 128, kN2_, 16384); \
  SB(); BARRIER(); LGKM0(); \
  MM(0, 1, b1); \
  SB(); BARRIER(); \
  /* ph7 */ \
  RD_A(1, 1); \
  if (!(LAST)) stage_half(Wg, n0, kN3_, 65536 + 32768); \
  SB(); BARRIER(); LGKM0(); \
  MM(1, 0, b0); \
  SB(); BARRIER(); \
  /* ph8 */ \
  if (!(LAST)) { stage_half(Wg, n0 + 128, kN3_, 65536 + 32768 + 16384); VMW(4); } \
  SB(); BARRIER(); \
  MM(1, 1, b1); \
  SB(); BARRIER(); \
} while (0)

// MODE 1: fused QKV epilogue (col<2048 Q bf16 | <2560 K bf16 | else Vb+Vf)
// MODE 2: fp32 C
template <int MODE>
__global__ __launch_bounds__(512, 2)
void gemm256(const bf16_t* __restrict__ Ag, const bf16_t* __restrict__ Wg,
             void* __restrict__ Cb, bf16_t* __restrict__ Kb, bf16_t* __restrict__ Vb,
             float* __restrict__ Vf, int M, int N, int K) {
  (void)M;
  __shared__ __align__(16) char lds[131072];
  const int tid  = threadIdx.x;
  const int wave = tid >> 6, lane = tid & 63;
  const int l16  = lane & 15, lg = lane >> 4;
  const int wm = wave >> 2, wn = wave & 3;         // 2 x 4 wave grid
  const int swz = (l16 & 7) << 4;                  // read-side XOR swizzle
  const int m0 = blockIdx.y * 256, n0 = blockIdx.x * 256;
  // staging: lane l fetches global col ((l&7)^(l>>3))*8 so the linear LDS
  // write (base + lane*16) lands at the swizzled slot the reads expect.
  const int srow = lane >> 3;
  const int scol = ((lane & 7) ^ srow) * 8;

  auto stage_half = [&](const bf16_t* __restrict__ X, int xrow, int k0, int ldsoff) {
    const bf16_t* src = X + (size_t)(xrow + wave * 16 + srow) * K + (k0 + scol);
    char* dst = lds + ldsoff + wave * 2048;
    g2l16(src, dst);
    g2l16(src + (size_t)8 * K, dst + 1024);
  };

  f32x4 acc[8][4] = {};
  bf16x8 a[4][2], b0[2][2], b1[2][2];

  // prologue: buf0 <- kt0 (A+W), buf1 <- kt1 (W only; A(b1) staged in ph1/2)
  stage_half(Ag, m0,        0, 0);
  stage_half(Ag, m0 + 128,  0, 16384);
  stage_half(Wg, n0,        0, 32768);
  stage_half(Wg, n0 + 128,  0, 32768 + 16384);
  stage_half(Wg, n0,       64, 65536 + 32768);
  stage_half(Wg, n0 + 128, 64, 65536 + 32768 + 16384);
  VMW(4);
  BARRIER();

  const int NIT = K >> 7;
  for (int it = 0; it < NIT - 1; ++it) {
    K_ITER(2 * it, 0);
  }
  K_ITER(2 * (NIT - 1), 1);

  // epilogue: C/D frag row=(lane>>4)*4+r, col=lane&15
#pragma unroll
  for (int mf = 0; mf < 8; mf++)
#pragma unroll
    for (int nf = 0; nf < 4; nf++) {
      const int row = m0 + wm * 128 + mf * 16 + lg * 4;
      const int col = n0 + wn * 64 + nf * 16 + l16;
#pragma unroll
      for (int r = 0; r < 4; r++) {
        float v = acc[mf][nf][r];
        if constexpr (MODE == 1) {
          if (col < 2048)      ((bf16_t*)Cb)[(size_t)(row + r) * 2048 + col] = (bf16_t)v;
          else if (col < 2560) Kb[(size_t)(row + r) * 512 + (col - 2048)] = (bf16_t)v;
          else {
            int c = col - 2560;
            Vb[(size_t)(row + r) * 512 + c] = (bf16_t)v;
            Vf[(size_t)(row + r) * 512 + c] = v;
          }
        } else {
          ((float*)Cb)[(size_t)(row + r) * N + col] = v;
        }
      }
    }
}

// ---------------------------------------------------------------------------
// Fused QK RMSNorm + NTK RoPE (+ q gain).  One wave per 128-elem head row.
// ---------------------------------------------------------------------------
__global__ __launch_bounds__(256)
void qk_norm_rope(bf16_t* __restrict__ Qp, bf16_t* __restrict__ Kp,
                  const float* __restrict__ gain) {
  const int lane = threadIdx.x & 63;
  int row = blockIdx.x * 4 + (threadIdx.x >> 6);
  bf16_t* Xp; int nh; bool ag;
  const int MQ = B_ * T_ * H_;
  if (row < MQ) { Xp = Qp; nh = H_;  ag = true; }
  else          { Xp = Kp; nh = HKV_; ag = false; row -= MQ; }
  const int h = row % nh;
  const int t = (row / nh) % T_;
  bf16_t* p = Xp + (size_t)row * D_;
  float x0 = (float)p[lane * 2 + 0];
  float x1 = (float)p[lane * 2 + 1];
  float ss = x0 * x0 + x1 * x1;
#pragma unroll
  for (int m = 32; m >= 1; m >>= 1) ss += __shfl_xor(ss, m);
  const float rn = rsqrtf(ss * (1.0f / 128.0f) + 1.1920929e-07f);
  x0 *= rn; x1 *= rn;
  const float y0 = __shfl_xor(x0, 32);
  const float y1 = __shfl_xor(x1, 32);
  const int i0 = (lane & 31) * 2;
  const float kfreq = -0.22349352180347601f;  // -log2(1e4*2^(128/126))/64
  float s0, c0, s1, c1;
  float a0 = (float)t * exp2f(kfreq * (float)i0);
  float a1 = (float)t * exp2f(kfreq * (float)(i0 + 1));
  sincosf(a0, &s0, &c0);
  sincosf(a1, &s1, &c1);
  float o0, o1;
  if (lane < 32) { o0 = x0 * c0 + y0 * s0;  o1 = x1 * c1 + y1 * s1; }
  else           { o0 = x0 * c0 - y0 * s0;  o1 = x1 * c1 - y1 * s1; }
  if (ag) { float g = gain[h]; o0 *= g; o1 *= g; }
  p[lane * 2 + 0] = (bf16_t)o0;
  p[lane * 2 + 1] = (bf16_t)o1;
}

// ---------------------------------------------------------------------------
// Causal GQA flash attention v4 — balanced pairing + global prefetch pipeline.
// ---------------------------------------------------------------------------
#define KLD 136  // K tile row stride (bf16): 128+8
#define VLD 72   // V^T tile row stride (bf16): 64+8
#define PLD 68   // P scratch row stride (fp32): 64+4

__global__ __launch_bounds__(256, 2)
void flash_attn(const bf16_t* __restrict__ Q, const bf16_t* __restrict__ Kg,
                const bf16_t* __restrict__ V, bf16_t* __restrict__ Y) {
  __shared__ bf16_t Ks[64 * KLD];
  __shared__ bf16_t Vs[D_ * VLD];      // [dim][key] transposed
  __shared__ float  Ps[4][16 * PLD];   // per-wave P scratch
  const int tid  = threadIdx.x;
  const int wave = tid >> 6, lane = tid & 63;
  const int l16  = lane & 15, lg = lane >> 4;
  const int b = blockIdx.z, h = blockIdx.y;
  const int pi = blockIdx.x;           // pair index 0..15
  const int hk = h >> 2;               // G = 4

  int qr[2];
  qr[0] = 64 * pi + 16 * wave;         // early tile (active while kb <= pi)
  qr[1] = 64 * (31 - pi) + 16 * wave;  // late tile (always active)

  bf16x8 qf[2][4];
#pragma unroll
  for (int mt = 0; mt < 2; mt++)
#pragma unroll
    for (int kk = 0; kk < 4; kk++)
      qf[mt][kk] = *(const bf16x8*)&Q[(((size_t)b * T_ + qr[mt] + l16) * H_ + h) * D_ + kk * 32 + lg * 8];

  f32x4 o[2][8] = {};
  float lsum[2][4] = {};
  const float C = 0.12752531f;  // (1/sqrt(128)) * log2(e)

  // staging coords
  const int sr = tid >> 4, sc = (tid & 15) * 8;  // K: 4 rows (sr+16j), 8-col chunks
  const int sp2 = (tid & 31) * 2;                // V: key pair
  const int dvh = (tid >> 5) * 8;                // V: dim chunk base

  bf16x8 kreg[4];
  bf16x8 vreg[2][2];
  auto pf_load = [&](int k0) {
#pragma unroll
    for (int j = 0; j < 4; j++)
      kreg[j] = *(const bf16x8*)&Kg[(((size_t)b * T_ + k0 + sr + 16 * j) * HKV_ + hk) * D_ + sc];
#pragma unroll
    for (int it = 0; it < 2; it++) {
      const bf16_t* vb = &V[(((size_t)b * T_ + k0 + sp2) * HKV_ + hk) * D_ + dvh + it * 64];
      vreg[it][0] = *(const bf16x8*)vb;
      vreg[it][1] = *(const bf16x8*)(vb + HKV_ * D_);
    }
  };
  auto pf_store = [&]() {
#pragma unroll
    for (int j = 0; j < 4; j++)
      *(bf16x8*)&Ks[(sr + 16 * j) * KLD + sc] = kreg[j];
#pragma unroll
    for (int it = 0; it < 2; it++) {
      int dd = dvh + it * 64;
      const unsigned short* au = (const unsigned short*)&vreg[it][0];
      const unsigned short* bu = (const unsigned short*)&vreg[it][1];
#pragma unroll
      for (int i = 0; i < 8; i++) {
        unsigned int pr = (unsigned int)au[i] | ((unsigned int)bu[i] << 16);
        *(unsigned int*)&Vs[(dd + i) * VLD + sp2] = pr;
      }
    }
  };

  const int nkb = 32 - pi;
  pf_load(0);
  for (int kb = 0; kb < nkb; kb++) {
    const int k0 = kb * 64;
    __syncthreads();   // prev iteration's LDS reads done
    pf_store();
    __syncthreads();   // tile visible to all waves
    if (kb + 1 < nkb) pf_load(k0 + 64);  // overlap with compute below

    const bool act0 = (kb <= pi);

    // ---- S = Q K^T ----
    f32x4 s[2][4] = {};
#pragma unroll
    for (int kk = 0; kk < 4; kk++) {
      bf16x8 kf[4];
#pragma unroll
      for (int f = 0; f < 4; f++)
        kf[f] = *(const bf16x8*)&Ks[(f * 16 + l16) * KLD + kk * 32 + lg * 8];
      if (act0)
#pragma unroll
        for (int f = 0; f < 4; f++)
          s[0][f] = __builtin_amdgcn_mfma_f32_16x16x32_bf16(qf[0][kk], kf[f], s[0][f], 0, 0, 0);
#pragma unroll
      for (int f = 0; f < 4; f++)
        s[1][f] = __builtin_amdgcn_mfma_f32_16x16x32_bf16(qf[1][kk], kf[f], s[1][f], 0, 0, 0);
    }
    // ---- softmax (static max; mask only on diagonal iteration) ----
    bf16x8 pf[2][2];
    float* pw = Ps[wave];
#pragma unroll
    for (int mt = 0; mt < 2; mt++) {
      if (mt == 0 && !act0) continue;
      const bool diag = (mt == 0) ? (kb == pi) : (kb == nkb - 1);
      if (diag) {
        const int myq = qr[mt] + lg * 4;
#pragma unroll
        for (int f = 0; f < 4; f++)
#pragma unroll
          for (int r = 0; r < 4; r++) {
            int kcol = k0 + f * 16 + l16;
            float p = (kcol <= myq + r) ? exp2f(s[mt][f][r] * C) : 0.0f;
            lsum[mt][r] += p;
            pw[(lg * 4 + r) * PLD + f * 16 + l16] = p;
          }
      } else {
#pragma unroll
        for (int f = 0; f < 4; f++)
#pragma unroll
          for (int r = 0; r < 4; r++) {
            float p = exp2f(s[mt][f][r] * C);
            lsum[mt][r] += p;
            pw[(lg * 4 + r) * PLD + f * 16 + l16] = p;
          }
      }
      __threadfence_block();
      f32x4 pa0 = *(const f32x4*)&pw[l16 * PLD + lg * 8];
      f32x4 pa1 = *(const f32x4*)&pw[l16 * PLD + lg * 8 + 4];
      f32x4 pb0 = *(const f32x4*)&pw[l16 * PLD + 32 + lg * 8];
      f32x4 pb1 = *(const f32x4*)&pw[l16 * PLD + 32 + lg * 8 + 4];
      pf[mt][0] = cvt8(pa0, pa1);
      pf[mt][1] = cvt8(pb0, pb1);
      __threadfence_block();
    }
    // ---- O += P V ----
#pragma unroll
    for (int f = 0; f < 8; f++) {
      bf16x8 v0 = *(const bf16x8*)&Vs[(f * 16 + l16) * VLD + lg * 8];
      bf16x8 v1 = *(const bf16x8*)&Vs[(f * 16 + l16) * VLD + 32 + lg * 8];
      if (act0) {
        o[0][f] = __builtin_amdgcn_mfma_f32_16x16x32_bf16(pf[0][0], v0, o[0][f], 0, 0, 0);
        o[0][f] = __builtin_amdgcn_mfma_f32_16x16x32_bf16(pf[0][1], v1, o[0][f], 0, 0, 0);
      }
      o[1][f] = __builtin_amdgcn_mfma_f32_16x16x32_bf16(pf[1][0], v0, o[1][f], 0, 0, 0);
      o[1][f] = __builtin_amdgcn_mfma_f32_16x16x32_bf16(pf[1][1], v1, o[1][f], 0, 0, 0);
    }
  }
  // ---- epilogue ----
#pragma unroll
  for (int mt = 0; mt < 2; mt++) {
    float rl[4];
#pragma unroll
    for (int r = 0; r < 4; r++) {
      float l = lsum[mt][r];
      l += __shfl_xor(l, 1);
      l += __shfl_xor(l, 2);
      l += __shfl_xor(l, 4);
      l += __shfl_xor(l, 8);
      rl[r] = 1.0f / l;
    }
#pragma unroll
    for (int f = 0; f < 8; f++)
#pragma unroll
      for (int r = 0; r < 4; r++) {
        int t = qr[mt] + lg * 4 + r;
        Y[(((size_t)b * T_ + t) * H_ + h) * D_ + f * 16 + l16] = (bf16_t)(o[mt][f][r] * rl[r]);
      }
  }
}

// ---------------------------------------------------------------------------
extern "C" void kernel_launch(void* const* d_in, const int* in_sizes, int n_in,
                              void* d_out, int out_size, void* d_ws, size_t ws_size,
                              hipStream_t stream) {
  (void)in_sizes; (void)n_in; (void)out_size;
  const float* x     = (const float*)d_in[0];
  const float* Wq    = (const float*)d_in[1];
  const float* Wk    = (const float*)d_in[2];
  const float* Wv    = (const float*)d_in[3];
  const float* Wproj = (const float*)d_in[4];
  const float* qgain = (const float*)d_in[5];

  float* out  = (float*)d_out;                  // [B,T,DIM] fp32
  float* vout = out + (size_t)B_ * T_ * DIM_;   // [B,T,HKV,D] fp32

  const size_t M = (size_t)B_ * T_;  // 4096
  char* ws = (char*)d_ws;
  size_t off = 0;
  auto take = [&](size_t elems) { bf16_t* p = (bf16_t*)(ws + off); off += elems * sizeof(bf16_t); return p; };

  bf16_t* Qp = take(M * DIM_);     // Q, later aliased as attention output Y
  bf16_t* Kp = take(M * KVDIM_);
  bf16_t* Vb = take(M * KVDIM_);

  const size_t cvt_elems = M * DIM_ + (size_t)3072 * DIM_ + (size_t)DIM_ * DIM_;
  const bool fast = (ws_size >= off + cvt_elems * sizeof(bf16_t));

  dim3 blk(256);
  if (fast) {
    bf16_t* xb     = take(M * DIM_);
    bf16_t* Wqkvb  = take((size_t)3072 * DIM_);  // Wq | Wk | Wv rows
    bf16_t* Wpb    = take((size_t)DIM_ * DIM_);

    cvt_all<<<dim3(9216), blk, 0, stream>>>(x, Wq, Wk, Wv, Wproj, xb, Wqkvb, Wpb);

    gemm256<1><<<dim3(3072 / 256, M / 256), dim3(512), 0, stream>>>(
        xb, Wqkvb, Qp, Kp, Vb, vout, (int)M, 3072, DIM_);

    qk_norm_rope<<<dim3((unsigned)((M * H_ + M * HKV_) / 4)), blk, 0, stream>>>(Qp, Kp, qgain);
    flash_attn<<<dim3(16, H_, B_), blk, 0, stream>>>(Qp, Kp, Vb, Qp);

    gemm256<2><<<dim3(DIM_ / 256, M / 256), dim3(512), 0, stream>>>(
        Qp, Wpb, out, nullptr, nullptr, nullptr, (int)M, DIM_, DIM_);
  } else {
    gemm128<0, false, false><<<dim3(DIM_ / 128, M / 128), blk, 0, stream>>>(
        x, Wq, nullptr, Qp, nullptr, nullptr, nullptr, M, DIM_, DIM_);
    gemm128<3, false, false><<<dim3(2 * KVDIM_ / 128, M / 128), blk, 0, stream>>>(
        x, Wk, Wv, Kp, nullptr, Vb, vout, M, 2 * KVDIM_, DIM_);
    qk_norm_rope<<<dim3((unsigned)((M * H_ + M * HKV_) / 4)), blk, 0, stream>>>(Qp, Kp, qgain);
    flash_attn<<<dim3(16, H_, B_), blk, 0, stream>>>(Qp, Kp, Vb, Qp);
    gemm128<2, true, false><<<dim3(DIM_ / 128, M / 128), blk, 0, stream>>>(
        Qp, Wproj, nullptr, out, nullptr, nullptr, nullptr, M, DIM_, DIM_);
  }
}

// Round 3
// 314.978 us; speedup vs baseline: 1.1133x; 1.0082x over previous
//
#include <hip/hip_runtime.h>
#include <hip/hip_bf16.h>

typedef __bf16 bf16_t;
typedef __bf16 bf16x4 __attribute__((ext_vector_type(4)));
typedef __bf16 bf16x8 __attribute__((ext_vector_type(8)));
typedef float f32x4 __attribute__((ext_vector_type(4)));

#define B_    2
#define T_    2048
#define DIM_  2048
#define H_    16
#define HKV_  4
#define D_    128
#define KVDIM_ 512

// ---- helpers --------------------------------------------------------------
__device__ __forceinline__ bf16x8 cvt8(f32x4 a, f32x4 b) {
  bf16x8 r;
  r[0] = (bf16_t)a[0]; r[1] = (bf16_t)a[1]; r[2] = (bf16_t)a[2]; r[3] = (bf16_t)a[3];
  r[4] = (bf16_t)b[0]; r[5] = (bf16_t)b[1]; r[6] = (bf16_t)b[2]; r[7] = (bf16_t)b[3];
  return r;
}
__device__ __forceinline__ bf16x4 cvt4(f32x4 a) {
  bf16x4 r;
  r[0] = (bf16_t)a[0]; r[1] = (bf16_t)a[1]; r[2] = (bf16_t)a[2]; r[3] = (bf16_t)a[3];
  return r;
}
// async global->LDS, 16B per lane; LDS dest = wave-uniform base + lane*16
__device__ __forceinline__ void g2l16(const void* g, void* l) {
  __builtin_amdgcn_global_load_lds(
      (const __attribute__((address_space(1))) unsigned int*)g,
      (__attribute__((address_space(3))) unsigned int*)l, 16, 0, 0);
}

// ---------------------------------------------------------------------------
// Fused fp32 -> bf16 convert (one launch).  2048-elem blocks.
// ---------------------------------------------------------------------------
__global__ __launch_bounds__(256)
void cvt_all(const float* __restrict__ x,  const float* __restrict__ wq,
             const float* __restrict__ wk, const float* __restrict__ wv,
             const float* __restrict__ wp, bf16_t* __restrict__ xb,
             bf16_t* __restrict__ wqkvb, bf16_t* __restrict__ wpb) {
  int blk = blockIdx.x;
  const float* s; bf16_t* d; int lb;
  if (blk < 4096)      { s = x;  d = xb;                              lb = blk; }
  else if (blk < 6144) { s = wq; d = wqkvb;                           lb = blk - 4096; }
  else if (blk < 6656) { s = wk; d = wqkvb + (size_t)2048 * DIM_;     lb = blk - 6144; }
  else if (blk < 7168) { s = wv; d = wqkvb + (size_t)2560 * DIM_;     lb = blk - 6656; }
  else                 { s = wp; d = wpb;                             lb = blk - 7168; }
  size_t i = (size_t)lb * 2048 + (size_t)threadIdx.x * 8;
  f32x4 a = *(const f32x4*)(s + i);
  f32x4 b = *(const f32x4*)(s + i + 4);
  *(bf16x8*)(d + i) = cvt8(a, b);
}

// ---------------------------------------------------------------------------
// Legacy 128x128 GEMM (kept for the fallback path).
// ---------------------------------------------------------------------------
template <int MODE, bool AASYNC, bool WASYNC>
__global__ __launch_bounds__(256)
void gemm128(const void* __restrict__ Ag, const void* __restrict__ Wg,
             const void* __restrict__ Wg2, void* __restrict__ Cb,
             bf16_t* __restrict__ Kb, bf16_t* __restrict__ Vb,
             float* __restrict__ Vf, int M, int N, int K) {
  constexpr int LDA = AASYNC ? 32 : 40;
  constexpr int LDW = WASYNC ? 32 : 40;
  __shared__ bf16_t As[128 * LDA];
  __shared__ bf16_t Ws[128 * LDW];
  const int tid  = threadIdx.x;
  const int wave = tid >> 6, lane = tid & 63;
  const int l16  = lane & 15, lg = lane >> 4;
  const int m0 = blockIdx.y * 128, n0 = blockIdx.x * 128;
  const int wm = (wave & 1) * 64, wn = (wave >> 1) * 64;
  f32x4 acc[4][4] = {};

  for (int k0 = 0; k0 < K; k0 += 32) {
    __syncthreads();
    if constexpr (AASYNC) {
      const bf16_t* A = (const bf16_t*)Ag;
      const int r = lane >> 2, c8 = (lane & 3) * 8;
      g2l16(&A[(size_t)(m0 + wave * 32 + r) * K + k0 + c8],      &As[(wave * 32) * LDA]);
      g2l16(&A[(size_t)(m0 + wave * 32 + 16 + r) * K + k0 + c8], &As[(wave * 32 + 16) * LDA]);
    } else {
      const float* A = (const float*)Ag;
#pragma unroll
      for (int j = 0; j < 4; j++) {
        int row = wave * 32 + j * 8 + (lane >> 3);
        int cf  = (lane & 7) * 4;
        f32x4 v = *(const f32x4*)&A[(size_t)(m0 + row) * K + k0 + cf];
        *(bf16x4*)&As[row * LDA + cf] = cvt4(v);
      }
    }
    if constexpr (WASYNC) {
      const bf16_t* W = (const bf16_t*)Wg;
      const int r = lane >> 2, c8 = (lane & 3) * 8;
      g2l16(&W[(size_t)(n0 + wave * 32 + r) * K + k0 + c8],      &Ws[(wave * 32) * LDW]);
      g2l16(&W[(size_t)(n0 + wave * 32 + 16 + r) * K + k0 + c8], &Ws[(wave * 32 + 16) * LDW]);
    } else {
      const float* W;
      int nb;
      if constexpr (MODE == 3) {
        if (n0 < 512) { W = (const float*)Wg;  nb = n0; }
        else          { W = (const float*)Wg2; nb = n0 - 512; }
      } else { W = (const float*)Wg; nb = n0; }
#pragma unroll
      for (int j = 0; j < 4; j++) {
        int row = wave * 32 + j * 8 + (lane >> 3);
        int cf  = (lane & 7) * 4;
        f32x4 v = *(const f32x4*)&W[(size_t)(nb + row) * K + k0 + cf];
        *(bf16x4*)&Ws[row * LDW + cf] = cvt4(v);
      }
    }
    __syncthreads();
    bf16x8 af[4], bfr[4];
#pragma unroll
    for (int i = 0; i < 4; i++)
      af[i] = *(const bf16x8*)&As[(wm + i * 16 + l16) * LDA + lg * 8];
#pragma unroll
    for (int j = 0; j < 4; j++)
      bfr[j] = *(const bf16x8*)&Ws[(wn + j * 16 + l16) * LDW + lg * 8];
#pragma unroll
    for (int i = 0; i < 4; i++)
#pragma unroll
      for (int j = 0; j < 4; j++)
        acc[i][j] = __builtin_amdgcn_mfma_f32_16x16x32_bf16(af[i], bfr[j], acc[i][j], 0, 0, 0);
  }
#pragma unroll
  for (int i = 0; i < 4; i++)
#pragma unroll
    for (int j = 0; j < 4; j++) {
      int row = m0 + wm + i * 16 + lg * 4;
      int col = n0 + wn + j * 16 + l16;
#pragma unroll
      for (int r = 0; r < 4; r++) {
        float v = acc[i][j][r];
        if constexpr (MODE == 0) {
          ((bf16_t*)Cb)[(size_t)(row + r) * N + col] = (bf16_t)v;
        } else if constexpr (MODE == 2) {
          ((float*)Cb)[(size_t)(row + r) * N + col] = v;
        } else if constexpr (MODE == 1) {
          if (col < 2048)      ((bf16_t*)Cb)[(size_t)(row + r) * 2048 + col] = (bf16_t)v;
          else if (col < 2560) Kb[(size_t)(row + r) * 512 + (col - 2048)] = (bf16_t)v;
          else {
            int c = col - 2560;
            Vb[(size_t)(row + r) * 512 + c] = (bf16_t)v;
            Vf[(size_t)(row + r) * 512 + c] = v;
          }
        } else {  // MODE 3
          if (col < 512) ((bf16_t*)Cb)[(size_t)(row + r) * 512 + col] = (bf16_t)v;
          else {
            int c = col - 512;
            Vb[(size_t)(row + r) * 512 + c] = (bf16_t)v;
            Vf[(size_t)(row + r) * 512 + c] = v;
          }
        }
      }
    }
}

// ---------------------------------------------------------------------------
// 256x256 8-phase GEMM (T2 swizzle + T3/T4 counted vmcnt + T5 setprio).
// vmcnt ledger (2 loads per stage_half):
//   ph4 wait(4): {prev ph7,ph8, ph1..ph4}=12 -> ph1/ph2 (A buf1) landed
//   ph8 wait(4): ph3..ph6 landed before next-iter ph1 reads buf0
//   last iter: wait(0) at ph4, no stages after.
// ---------------------------------------------------------------------------
#define SB() __builtin_amdgcn_sched_barrier(0)
#define BARRIER() __builtin_amdgcn_s_barrier()
#define LGKM0() do { asm volatile("s_waitcnt lgkmcnt(0)" ::: "memory"); SB(); } while (0)
#define VMW(N) do { asm volatile("s_waitcnt vmcnt(" #N ")" ::: "memory"); SB(); } while (0)

#define RD_A(BUF, QM) do { \
  _Pragma("unroll") for (int f_ = 0; f_ < 4; f_++) { \
    const int r_ = wm * 128 + (QM) * 64 + f_ * 16 + l16; \
    _Pragma("unroll") for (int ks_ = 0; ks_ < 2; ks_++) \
      a[f_][ks_] = *(const bf16x8*)(lds + (BUF) * 65536 + r_ * 128 + ((ks_ * 64 + lg * 16) ^ swz)); \
  } } while (0)

#define RD_B(BUF, QN, BB) do { \
  _Pragma("unroll") for (int n_ = 0; n_ < 2; n_++) { \
    const int r_ = wn * 64 + (QN) * 32 + n_ * 16 + l16; \
    _Pragma("unroll") for (int ks_ = 0; ks_ < 2; ks_++) \
      BB[n_][ks_] = *(const bf16x8*)(lds + (BUF) * 65536 + 32768 + r_ * 128 + ((ks_ * 64 + lg * 16) ^ swz)); \
  } } while (0)

#define MM(QM, QN, BB) do { \
  __builtin_amdgcn_s_setprio(1); \
  _Pragma("unroll") for (int f_ = 0; f_ < 4; f_++) \
    _Pragma("unroll") for (int n_ = 0; n_ < 2; n_++) \
      _Pragma("unroll") for (int ks_ = 0; ks_ < 2; ks_++) \
        acc[(QM) * 4 + f_][(QN) * 2 + n_] = __builtin_amdgcn_mfma_f32_16x16x32_bf16( \
            a[f_][ks_], BB[n_][ks_], acc[(QM) * 4 + f_][(QN) * 2 + n_], 0, 0, 0); \
  __builtin_amdgcn_s_setprio(0); \
  } while (0)

#define K_ITER(KT0, LAST) do { \
  const int kA1_ = ((KT0) + 1) * 64; \
  const int kN2_ = ((KT0) + 2) * 64; \
  const int kN3_ = ((KT0) + 3) * 64; \
  /* ph1 */ \
  RD_A(0, 0); RD_B(0, 0, b0); \
  stage_half(Ag, m0, kA1_, 65536); \
  asm volatile("s_waitcnt lgkmcnt(8)" ::: "memory"); \
  SB(); BARRIER(); LGKM0(); \
  MM(0, 0, b0); \
  SB(); BARRIER(); \
  /* ph2 */ \
  RD_B(0, 1, b1); \
  stage_half(Ag, m0 + 128, kA1_, 65536 + 16384); \
  SB(); BARRIER(); LGKM0(); \
  MM(0, 1, b1); \
  SB(); BARRIER(); \
  /* ph3 */ \
  RD_A(0, 1); \
  if (!(LAST)) stage_half(Wg, n0, kN2_, 32768); \
  SB(); BARRIER(); LGKM0(); \
  MM(1, 0, b0); \
  SB(); BARRIER(); \
  /* ph4 */ \
  if (!(LAST)) { stage_half(Wg, n0 + 128, kN2_, 32768 + 16384); VMW(4); } \
  else { VMW(0); } \
  SB(); BARRIER(); \
  MM(1, 1, b1); \
  SB(); BARRIER(); \
  /* ph5 */ \
  RD_A(1, 0); RD_B(1, 0, b0); \
  if (!(LAST)) stage_half(Ag, m0, kN2_, 0); \
  asm volatile("s_waitcnt lgkmcnt(8)" ::: "memory"); \
  SB(); BARRIER(); LGKM0(); \
  MM(0, 0, b0); \
  SB(); BARRIER(); \
  /* ph6 */ \
  RD_B(1, 1, b1); \
  if (!(LAST)) stage_half(Ag, m0 + 128, kN2_, 16384); \
  SB(); BARRIER(); LGKM0(); \
  MM(0, 1, b1); \
  SB(); BARRIER(); \
  /* ph7 */ \
  RD_A(1, 1); \
  if (!(LAST)) stage_half(Wg, n0, kN3_, 65536 + 32768); \
  SB(); BARRIER(); LGKM0(); \
  MM(1, 0, b0); \
  SB(); BARRIER(); \
  /* ph8 */ \
  if (!(LAST)) { stage_half(Wg, n0 + 128, kN3_, 65536 + 32768 + 16384); VMW(4); } \
  SB(); BARRIER(); \
  MM(1, 1, b1); \
  SB(); BARRIER(); \
} while (0)

// MODE 1: fused QKV epilogue (col<2048 Q bf16 | <2560 K bf16 | else Vb+Vf)
// MODE 2: fp32 C
template <int MODE>
__global__ __launch_bounds__(512, 2)
void gemm256(const bf16_t* __restrict__ Ag, const bf16_t* __restrict__ Wg,
             void* __restrict__ Cb, bf16_t* __restrict__ Kb, bf16_t* __restrict__ Vb,
             float* __restrict__ Vf, int M, int N, int K) {
  (void)M;
  __shared__ __align__(16) char lds[131072];
  const int tid  = threadIdx.x;
  const int wave = tid >> 6, lane = tid & 63;
  const int l16  = lane & 15, lg = lane >> 4;
  const int wm = wave >> 2, wn = wave & 3;         // 2 x 4 wave grid
  const int swz = (l16 & 7) << 4;                  // read-side XOR swizzle
  const int m0 = blockIdx.y * 256, n0 = blockIdx.x * 256;
  // staging: lane l fetches global col ((l&7)^(l>>3))*8 so the linear LDS
  // write (base + lane*16) lands at the swizzled slot the reads expect.
  const int srow = lane >> 3;
  const int scol = ((lane & 7) ^ srow) * 8;

  auto stage_half = [&](const bf16_t* __restrict__ X, int xrow, int k0, int ldsoff) {
    const bf16_t* src = X + (size_t)(xrow + wave * 16 + srow) * K + (k0 + scol);
    char* dst = lds + ldsoff + wave * 2048;
    g2l16(src, dst);
    g2l16(src + (size_t)8 * K, dst + 1024);
  };

  f32x4 acc[8][4] = {};
  bf16x8 a[4][2], b0[2][2], b1[2][2];

  // prologue: buf0 <- kt0 (A+W), buf1 <- kt1 (W only; A(b1) staged in ph1/2)
  stage_half(Ag, m0,        0, 0);
  stage_half(Ag, m0 + 128,  0, 16384);
  stage_half(Wg, n0,        0, 32768);
  stage_half(Wg, n0 + 128,  0, 32768 + 16384);
  stage_half(Wg, n0,       64, 65536 + 32768);
  stage_half(Wg, n0 + 128, 64, 65536 + 32768 + 16384);
  VMW(4);
  BARRIER();

  const int NIT = K >> 7;
  for (int it = 0; it < NIT - 1; ++it) {
    K_ITER(2 * it, 0);
  }
  K_ITER(2 * (NIT - 1), 1);

  // epilogue: C/D frag row=(lane>>4)*4+r, col=lane&15
#pragma unroll
  for (int mf = 0; mf < 8; mf++)
#pragma unroll
    for (int nf = 0; nf < 4; nf++) {
      const int row = m0 + wm * 128 + mf * 16 + lg * 4;
      const int col = n0 + wn * 64 + nf * 16 + l16;
#pragma unroll
      for (int r = 0; r < 4; r++) {
        float v = acc[mf][nf][r];
        if constexpr (MODE == 1) {
          if (col < 2048)      ((bf16_t*)Cb)[(size_t)(row + r) * 2048 + col] = (bf16_t)v;
          else if (col < 2560) Kb[(size_t)(row + r) * 512 + (col - 2048)] = (bf16_t)v;
          else {
            int c = col - 2560;
            Vb[(size_t)(row + r) * 512 + c] = (bf16_t)v;
            Vf[(size_t)(row + r) * 512 + c] = v;
          }
        } else {
          ((float*)Cb)[(size_t)(row + r) * N + col] = v;
        }
      }
    }
}

// ---------------------------------------------------------------------------
// Fused QK RMSNorm + NTK RoPE (+ q gain).  One wave per 128-elem head row.
// ---------------------------------------------------------------------------
__global__ __launch_bounds__(256)
void qk_norm_rope(bf16_t* __restrict__ Qp, bf16_t* __restrict__ Kp,
                  const float* __restrict__ gain) {
  const int lane = threadIdx.x & 63;
  int row = blockIdx.x * 4 + (threadIdx.x >> 6);
  bf16_t* Xp; int nh; bool ag;
  const int MQ = B_ * T_ * H_;
  if (row < MQ) { Xp = Qp; nh = H_;  ag = true; }
  else          { Xp = Kp; nh = HKV_; ag = false; row -= MQ; }
  const int h = row % nh;
  const int t = (row / nh) % T_;
  bf16_t* p = Xp + (size_t)row * D_;
  float x0 = (float)p[lane * 2 + 0];
  float x1 = (float)p[lane * 2 + 1];
  float ss = x0 * x0 + x1 * x1;
#pragma unroll
  for (int m = 32; m >= 1; m >>= 1) ss += __shfl_xor(ss, m);
  const float rn = rsqrtf(ss * (1.0f / 128.0f) + 1.1920929e-07f);
  x0 *= rn; x1 *= rn;
  const float y0 = __shfl_xor(x0, 32);
  const float y1 = __shfl_xor(x1, 32);
  const int i0 = (lane & 31) * 2;
  const float kfreq = -0.22349352180347601f;  // -log2(1e4*2^(128/126))/64
  float s0, c0, s1, c1;
  float a0 = (float)t * exp2f(kfreq * (float)i0);
  float a1 = (float)t * exp2f(kfreq * (float)(i0 + 1));
  sincosf(a0, &s0, &c0);
  sincosf(a1, &s1, &c1);
  float o0, o1;
  if (lane < 32) { o0 = x0 * c0 + y0 * s0;  o1 = x1 * c1 + y1 * s1; }
  else           { o0 = x0 * c0 - y0 * s0;  o1 = x1 * c1 - y1 * s1; }
  if (ag) { float g = gain[h]; o0 *= g; o1 *= g; }
  p[lane * 2 + 0] = (bf16_t)o0;
  p[lane * 2 + 1] = (bf16_t)o1;
}

// ---------------------------------------------------------------------------
// Causal GQA flash attention v5 — swapped QK^T + permuted-V zero-shuffle PV.
// S^T = mfma(K,Q): lane(g,l16) holds P[k=f*16+4g+r][q=l16].  V is staged into
// LDS with key-slot permutation slot=[k3 k2 k4 k1 k0] (per 32-key half) so the
// lane's own exp'd values, packed via cvt8, ARE the PV A-fragment.  No P LDS
// round-trip, no cross-lane exchange.
// ---------------------------------------------------------------------------
#define KLD 136  // K tile row stride (bf16): 128+8
#define VLD 72   // V^T tile row stride (bf16): 64+8

__global__ __launch_bounds__(256, 2)
void flash_attn(const bf16_t* __restrict__ Q, const bf16_t* __restrict__ Kg,
                const bf16_t* __restrict__ V, bf16_t* __restrict__ Y) {
  __shared__ bf16_t Ks[64 * KLD];
  __shared__ bf16_t Vs[D_ * VLD];      // [dim][key-slot] transposed+permuted
  const int tid  = threadIdx.x;
  const int wave = tid >> 6, lane = tid & 63;
  const int l16  = lane & 15, lg = lane >> 4;
  const int b = blockIdx.z, h = blockIdx.y;
  const int pi = blockIdx.x;           // pair index 0..15
  const int hk = h >> 2;               // G = 4

  int qr[2];
  qr[0] = 64 * pi + 16 * wave;         // early tile (active while kb <= pi)
  qr[1] = 64 * (31 - pi) + 16 * wave;  // late tile (always active)

  bf16x8 qf[2][4];
#pragma unroll
  for (int mt = 0; mt < 2; mt++)
#pragma unroll
    for (int kk = 0; kk < 4; kk++)
      qf[mt][kk] = *(const bf16x8*)&Q[(((size_t)b * T_ + qr[mt] + l16) * H_ + h) * D_ + kk * 32 + lg * 8];

  f32x4 o[2][8] = {};
  float lsum[2] = {};
  const float C = 0.12752531f;  // (1/sqrt(128)) * log2(e)

  // staging coords
  const int sr = tid >> 4, sc = (tid & 15) * 8;  // K: 4 rows (sr+16j), 8-col chunks
  const int sp2 = (tid & 31) * 2;                // V: key pair (even)
  const int dvh = (tid >> 5) * 8;                // V: dim chunk base
  // key-slot permutation within each 32-key half: slot = [k3 k2 k4 k1 k0]
  const int ssl = (sp2 & 3) | (((sp2 >> 4) & 1) << 2) | (((sp2 >> 2) & 1) << 3)
                | (((sp2 >> 3) & 1) << 4) | (sp2 & 32);

  bf16x8 kreg[4];
  bf16x8 vreg[2][2];
  auto pf_load = [&](int k0) {
#pragma unroll
    for (int j = 0; j < 4; j++)
      kreg[j] = *(const bf16x8*)&Kg[(((size_t)b * T_ + k0 + sr + 16 * j) * HKV_ + hk) * D_ + sc];
#pragma unroll
    for (int it = 0; it < 2; it++) {
      const bf16_t* vb = &V[(((size_t)b * T_ + k0 + sp2) * HKV_ + hk) * D_ + dvh + it * 64];
      vreg[it][0] = *(const bf16x8*)vb;
      vreg[it][1] = *(const bf16x8*)(vb + HKV_ * D_);
    }
  };
  auto pf_store = [&]() {
#pragma unroll
    for (int j = 0; j < 4; j++)
      *(bf16x8*)&Ks[(sr + 16 * j) * KLD + sc] = kreg[j];
#pragma unroll
    for (int it = 0; it < 2; it++) {
      int dd = dvh + it * 64;
      const unsigned short* au = (const unsigned short*)&vreg[it][0];
      const unsigned short* bu = (const unsigned short*)&vreg[it][1];
#pragma unroll
      for (int i = 0; i < 8; i++) {
        unsigned int pr = (unsigned int)au[i] | ((unsigned int)bu[i] << 16);
        *(unsigned int*)&Vs[(dd + i) * VLD + ssl] = pr;
      }
    }
  };

  const int nkb = 32 - pi;
  pf_load(0);
  for (int kb = 0; kb < nkb; kb++) {
    const int k0 = kb * 64;
    __syncthreads();   // prev iteration's LDS reads done
    pf_store();
    __syncthreads();   // tile visible to all waves
    if (kb + 1 < nkb) pf_load(k0 + 64);  // overlap with compute below

    const bool act0 = (kb <= pi);

    // ---- S^T = K Q^T : lane(g,l16): s[mt][f][r] = S[k=k0+f*16+4g+r][q=qr+l16]
    f32x4 s[2][4] = {};
#pragma unroll
    for (int kk = 0; kk < 4; kk++) {
      bf16x8 kf[4];
#pragma unroll
      for (int f = 0; f < 4; f++)
        kf[f] = *(const bf16x8*)&Ks[(f * 16 + l16) * KLD + kk * 32 + lg * 8];
      if (act0)
#pragma unroll
        for (int f = 0; f < 4; f++)
          s[0][f] = __builtin_amdgcn_mfma_f32_16x16x32_bf16(kf[f], qf[0][kk], s[0][f], 0, 0, 0);
#pragma unroll
      for (int f = 0; f < 4; f++)
        s[1][f] = __builtin_amdgcn_mfma_f32_16x16x32_bf16(kf[f], qf[1][kk], s[1][f], 0, 0, 0);
    }
    // ---- softmax (static max; in-register, in-place exp into s) ----
    bf16x8 pfr[2][2];
#pragma unroll
    for (int mt = 0; mt < 2; mt++) {
      if (mt == 0 && !act0) continue;
      const bool diag = (mt == 0) ? (kb == pi) : (kb == nkb - 1);
      const int myq = qr[mt] + l16;
      if (diag) {
#pragma unroll
        for (int f = 0; f < 4; f++)
#pragma unroll
          for (int r = 0; r < 4; r++) {
            int kg = k0 + f * 16 + lg * 4 + r;
            float p = (kg <= myq) ? exp2f(s[mt][f][r] * C) : 0.0f;
            lsum[mt] += p;
            s[mt][f][r] = p;
          }
      } else {
#pragma unroll
        for (int f = 0; f < 4; f++)
#pragma unroll
          for (int r = 0; r < 4; r++) {
            float p = exp2f(s[mt][f][r] * C);
            lsum[mt] += p;
            s[mt][f][r] = p;
          }
      }
      // A-frag for PV: slice ks keys, lane's own values in key-slot order.
      pfr[mt][0] = cvt8(s[mt][0], s[mt][1]);
      pfr[mt][1] = cvt8(s[mt][2], s[mt][3]);
    }
    // ---- O += P V  (V read in permuted key-slot order) ----
#pragma unroll
    for (int f = 0; f < 8; f++) {
      bf16x8 v0 = *(const bf16x8*)&Vs[(f * 16 + l16) * VLD + lg * 8];
      bf16x8 v1 = *(const bf16x8*)&Vs[(f * 16 + l16) * VLD + 32 + lg * 8];
      if (act0) {
        o[0][f] = __builtin_amdgcn_mfma_f32_16x16x32_bf16(pfr[0][0], v0, o[0][f], 0, 0, 0);
        o[0][f] = __builtin_amdgcn_mfma_f32_16x16x32_bf16(pfr[0][1], v1, o[0][f], 0, 0, 0);
      }
      o[1][f] = __builtin_amdgcn_mfma_f32_16x16x32_bf16(pfr[1][0], v0, o[1][f], 0, 0, 0);
      o[1][f] = __builtin_amdgcn_mfma_f32_16x16x32_bf16(pfr[1][1], v1, o[1][f], 0, 0, 0);
    }
  }
  // ---- epilogue: lsum lives at q=l16; O rows are q=lg*4+r ----
#pragma unroll
  for (int mt = 0; mt < 2; mt++) {
    float l = lsum[mt];
    l += __shfl_xor(l, 16);
    l += __shfl_xor(l, 32);
    const float inv = 1.0f / l;
    float rlv[4];
#pragma unroll
    for (int r = 0; r < 4; r++) rlv[r] = __shfl(inv, lg * 4 + r);
#pragma unroll
    for (int f = 0; f < 8; f++)
#pragma unroll
      for (int r = 0; r < 4; r++) {
        int t = qr[mt] + lg * 4 + r;
        Y[(((size_t)b * T_ + t) * H_ + h) * D_ + f * 16 + l16] = (bf16_t)(o[mt][f][r] * rlv[r]);
      }
  }
}

// ---------------------------------------------------------------------------
extern "C" void kernel_launch(void* const* d_in, const int* in_sizes, int n_in,
                              void* d_out, int out_size, void* d_ws, size_t ws_size,
                              hipStream_t stream) {
  (void)in_sizes; (void)n_in; (void)out_size;
  const float* x     = (const float*)d_in[0];
  const float* Wq    = (const float*)d_in[1];
  const float* Wk    = (const float*)d_in[2];
  const float* Wv    = (const float*)d_in[3];
  const float* Wproj = (const float*)d_in[4];
  const float* qgain = (const float*)d_in[5];

  float* out  = (float*)d_out;                  // [B,T,DIM] fp32
  float* vout = out + (size_t)B_ * T_ * DIM_;   // [B,T,HKV,D] fp32

  const size_t M = (size_t)B_ * T_;  // 4096
  char* ws = (char*)d_ws;
  size_t off = 0;
  auto take = [&](size_t elems) { bf16_t* p = (bf16_t*)(ws + off); off += elems * sizeof(bf16_t); return p; };

  bf16_t* Qp = take(M * DIM_);     // Q, later aliased as attention output Y
  bf16_t* Kp = take(M * KVDIM_);
  bf16_t* Vb = take(M * KVDIM_);

  const size_t cvt_elems = M * DIM_ + (size_t)3072 * DIM_ + (size_t)DIM_ * DIM_;
  const bool fast = (ws_size >= off + cvt_elems * sizeof(bf16_t));

  dim3 blk(256);
  if (fast) {
    bf16_t* xb     = take(M * DIM_);
    bf16_t* Wqkvb  = take((size_t)3072 * DIM_);  // Wq | Wk | Wv rows
    bf16_t* Wpb    = take((size_t)DIM_ * DIM_);

    cvt_all<<<dim3(9216), blk, 0, stream>>>(x, Wq, Wk, Wv, Wproj, xb, Wqkvb, Wpb);

    gemm256<1><<<dim3(3072 / 256, M / 256), dim3(512), 0, stream>>>(
        xb, Wqkvb, Qp, Kp, Vb, vout, (int)M, 3072, DIM_);

    qk_norm_rope<<<dim3((unsigned)((M * H_ + M * HKV_) / 4)), blk, 0, stream>>>(Qp, Kp, qgain);
    flash_attn<<<dim3(16, H_, B_), blk, 0, stream>>>(Qp, Kp, Vb, Qp);

    gemm256<2><<<dim3(DIM_ / 256, M / 256), dim3(512), 0, stream>>>(
        Qp, Wpb, out, nullptr, nullptr, nullptr, (int)M, DIM_, DIM_);
  } else {
    gemm128<0, false, false><<<dim3(DIM_ / 128, M / 128), blk, 0, stream>>>(
        x, Wq, nullptr, Qp, nullptr, nullptr, nullptr, M, DIM_, DIM_);
    gemm128<3, false, false><<<dim3(2 * KVDIM_ / 128, M / 128), blk, 0, stream>>>(
        x, Wk, Wv, Kp, nullptr, Vb, vout, M, 2 * KVDIM_, DIM_);
    qk_norm_rope<<<dim3((unsigned)((M * H_ + M * HKV_) / 4)), blk, 0, stream>>>(Qp, Kp, qgain);
    flash_attn<<<dim3(16, H_, B_), blk, 0, stream>>>(Qp, Kp, Vb, Qp);
    gemm128<2, true, false><<<dim3(DIM_ / 128, M / 128), blk, 0, stream>>>(
        Qp, Wproj, nullptr, out, nullptr, nullptr, nullptr, M, DIM_, DIM_);
  }
}